// Round 1
// baseline (90.668 us; speedup 1.0000x reference)
//
#include <hip/hip_runtime.h>
#include <cstdint>

// Problem constants (B=4, L=4096, D=3, VOCAB=8192)
#define N_ROWS   16384
#define VOCAB    8192
#define CHUNK    1024
#define BLOCK    256
#define NCHUNK   (VOCAB / CHUNK)   // 8
#define NRB      (N_ROWS / BLOCK)  // 64

// d_out layout (floats): [0,49152) quant_ste | [49152,65536) idx as float | [65536] vq_loss
// d_ws layout: [0, 16384*8) u64 argmin keys | [131072, +256) 64 float block partials

// ---------------------------------------------------------------------------
// Kernel 1: per-(row-block, vocab-chunk) distance scan + atomicMin on packed key.
// key = (float_bits(dist) << 32) | global_idx  -> min key == (min dist, then min idx)
// which exactly reproduces np.argmin first-index tie-breaking.
// ---------------------------------------------------------------------------
__global__ __launch_bounds__(BLOCK) void vq_dist_kernel(
    const float* __restrict__ feats, const float* __restrict__ emb,
    unsigned long long* __restrict__ keys)
{
    __shared__ float4 sE[CHUNK];   // 16 KiB: (e0, e1, e2, ||e||^2)

    const int chunk = blockIdx.y;
    const int vbase = chunk * CHUNK;

    for (int i = threadIdx.x; i < CHUNK; i += BLOCK) {
        const int v = vbase + i;
        const float e0 = emb[3 * v + 0];
        const float e1 = emb[3 * v + 1];
        const float e2 = emb[3 * v + 2];
        // np: sum(emb*emb, axis=1): round each product, then left-to-right add
        const float ee = __fadd_rn(__fadd_rn(__fmul_rn(e0, e0), __fmul_rn(e1, e1)),
                                   __fmul_rn(e2, e2));
        sE[i] = make_float4(e0, e1, e2, ee);
    }
    __syncthreads();

    const int row = blockIdx.x * BLOCK + threadIdx.x;   // N_ROWS is a multiple of BLOCK
    const float x0 = feats[3 * row + 0];
    const float x1 = feats[3 * row + 1];
    const float x2 = feats[3 * row + 2];
    const float xx = __fadd_rn(__fadd_rn(__fmul_rn(x0, x0), __fmul_rn(x1, x1)),
                               __fmul_rn(x2, x2));

    float best = __int_as_float(0x7f800000);  // +inf
    int   bidx = 0;

    #pragma unroll 8
    for (int i = 0; i < CHUNK; ++i) {
        const float4 E = sE[i];   // uniform address across wave -> LDS broadcast
        const float xe = __fmaf_rn(x2, E.z, __fmaf_rn(x1, E.y, __fmul_rn(x0, E.x)));
        // np: dist = (xx - 2*xe) + ee, with each step rounded
        const float d = __fadd_rn(__fsub_rn(xx, __fmul_rn(2.0f, xe)), E.w);
        if (d < best) { best = d; bidx = i; }   // strict < keeps first index on ties
    }

    const unsigned long long key =
        ((unsigned long long)__float_as_uint(best) << 32) |
        (unsigned long long)(unsigned)(vbase + bidx);
    atomicMin(&keys[row], key);
}

// ---------------------------------------------------------------------------
// Kernel 2: finalize — gather codebook row, write quant_ste + idx, per-block
// partial sum of squared (quant - feats).
// ---------------------------------------------------------------------------
__global__ __launch_bounds__(BLOCK) void vq_finalize_kernel(
    const float* __restrict__ feats, const float* __restrict__ emb,
    const unsigned long long* __restrict__ keys,
    float* __restrict__ out_quant, float* __restrict__ out_idx,
    float* __restrict__ partial)
{
    const int row = blockIdx.x * BLOCK + threadIdx.x;
    const unsigned long long key = keys[row];
    const unsigned idx = (unsigned)(key & 0xffffffffULL);

    const float x0 = feats[3 * row + 0];
    const float x1 = feats[3 * row + 1];
    const float x2 = feats[3 * row + 2];
    const float e0 = emb[3 * idx + 0];
    const float e1 = emb[3 * idx + 1];
    const float e2 = emb[3 * idx + 2];

    // quant_ste = feats + (quant - feats), replicating fp32 rounding of the reference
    out_quant[3 * row + 0] = __fadd_rn(x0, __fsub_rn(e0, x0));
    out_quant[3 * row + 1] = __fadd_rn(x1, __fsub_rn(e1, x1));
    out_quant[3 * row + 2] = __fadd_rn(x2, __fsub_rn(e2, x2));
    out_idx[row] = (float)idx;

    const float d0 = e0 - x0, d1 = e1 - x1, d2 = e2 - x2;
    float s = d0 * d0 + d1 * d1 + d2 * d2;

    // wave64 reduce
    #pragma unroll
    for (int off = 32; off > 0; off >>= 1) s += __shfl_down(s, off, 64);

    __shared__ float wsum[BLOCK / 64];
    if ((threadIdx.x & 63) == 0) wsum[threadIdx.x >> 6] = s;
    __syncthreads();
    if (threadIdx.x == 0)
        partial[blockIdx.x] = (wsum[0] + wsum[1]) + (wsum[2] + wsum[3]);
}

// ---------------------------------------------------------------------------
// Kernel 3: sum the 64 block partials -> vq_loss = m + 0.25*m, m = mean(sq)
// ---------------------------------------------------------------------------
__global__ void vq_loss_kernel(const float* __restrict__ partial,
                               float* __restrict__ out_loss)
{
    float s = partial[threadIdx.x];   // 64 threads, NRB == 64
    #pragma unroll
    for (int off = 32; off > 0; off >>= 1) s += __shfl_down(s, off, 64);
    if (threadIdx.x == 0) {
        const float m = s / (float)(N_ROWS * 3);
        out_loss[0] = __fadd_rn(m, __fmul_rn(0.25f, m));
    }
}

extern "C" void kernel_launch(void* const* d_in, const int* in_sizes, int n_in,
                              void* d_out, int out_size, void* d_ws, size_t ws_size,
                              hipStream_t stream)
{
    const float* feats = (const float*)d_in[0];   // [4,4096,3] f32
    const float* emb   = (const float*)d_in[1];   // [8192,3]   f32
    float* out = (float*)d_out;

    unsigned long long* keys = (unsigned long long*)d_ws;
    float* partial = (float*)((char*)d_ws + (size_t)N_ROWS * 8);

    // init argmin keys to all-ones (max u64); ws is poisoned 0xAA before every call
    hipMemsetAsync(d_ws, 0xFF, (size_t)N_ROWS * 8, stream);

    vq_dist_kernel<<<dim3(NRB, NCHUNK), BLOCK, 0, stream>>>(feats, emb, keys);
    vq_finalize_kernel<<<NRB, BLOCK, 0, stream>>>(
        feats, emb, keys, out, out + (size_t)N_ROWS * 3, partial);
    vq_loss_kernel<<<1, 64, 0, stream>>>(partial, out + (size_t)N_ROWS * 4);
}

// Round 2
// 83.315 us; speedup vs baseline: 1.0883x; 1.0883x over previous
//
#include <hip/hip_runtime.h>
#include <cstdint>

// B=4, L=4096, D=3, VOCAB=8192
#define N_ROWS   16384
#define VOCAB    8192
#define BLOCK    512          // 8 waves
#define ROWS_PB  32           // rows per block (tid>>4)
#define NPIECE   8
#define PIECE    1024         // codes staged per piece (16 KiB as float4)
#define GRID     (N_ROWS / ROWS_PB)   // 512 blocks

typedef unsigned long long u64;

// d_out layout (floats): [0,49152) quant_ste | [49152,65536) idx as float | [65536] vq_loss
// d_ws: [0, GRID*4) float block partials

// ---------------------------------------------------------------------------
// Fused kernel: distance scan + argmin + gather + quant_ste + idx + block loss
// partial. Thread (r,c): r = tid>>4 owns one row, c = tid&15 scans codes
// code ≡ c (mod 16). Packed u64 key (dist_bits<<32 | idx) gives exact
// np.argmin first-index tie-breaking under shfl_xor min-reduction.
// Distance formula is bit-frozen to the np reference (R1: absmax 0.0).
// ---------------------------------------------------------------------------
__global__ __launch_bounds__(BLOCK, 4) void vq_main_kernel(
    const float* __restrict__ feats, const float* __restrict__ emb,
    float* __restrict__ out_quant, float* __restrict__ out_idx,
    float* __restrict__ partial)
{
    __shared__ float4 sE[PIECE];          // (e0,e1,e2,||e||^2)
    __shared__ float  wsum[BLOCK / 64];

    const int tid = threadIdx.x;
    const int c   = tid & 15;
    const int row = blockIdx.x * ROWS_PB + (tid >> 4);

    const float x0 = feats[3 * row + 0];
    const float x1 = feats[3 * row + 1];
    const float x2 = feats[3 * row + 2];
    const float xx = __fadd_rn(__fadd_rn(__fmul_rn(x0, x0), __fmul_rn(x1, x1)),
                               __fmul_rn(x2, x2));

    // reg-staged prefetch of piece 0 (2 codes per thread: tid and tid+512)
    const float* g = emb + 3 * tid;
    float a0 = g[0],    a1 = g[1],    a2 = g[2];
    float b0 = g[1536], b1 = g[1537], b2 = g[1538];

    float best = __int_as_float(0x7f800000);   // +inf
    int   bj   = 0;                            // best (piece*64 + j)

    for (int p = 0; p < NPIECE; ++p) {
        __syncthreads();   // previous piece fully consumed before overwrite
        sE[tid] = make_float4(a0, a1, a2,
            __fadd_rn(__fadd_rn(__fmul_rn(a0, a0), __fmul_rn(a1, a1)), __fmul_rn(a2, a2)));
        sE[tid + BLOCK] = make_float4(b0, b1, b2,
            __fadd_rn(__fadd_rn(__fmul_rn(b0, b0), __fmul_rn(b1, b1)), __fmul_rn(b2, b2)));
        __syncthreads();

        // issue next piece's global loads; latency hides under the 64-iter scan
        if (p + 1 < NPIECE) {
            const float* gn = emb + 3 * ((p + 1) * PIECE + tid);
            a0 = gn[0];    a1 = gn[1];    a2 = gn[2];
            b0 = gn[1536]; b1 = gn[1537]; b2 = gn[1538];
        }

        float pbest = __int_as_float(0x7f800000);
        int   pj    = 0;
        #pragma unroll
        for (int j = 0; j < 64; ++j) {
            const float4 E = sE[j * 16 + c];   // base + imm offset; 2-way bank alias (free)
            const float xe = __fmaf_rn(x2, E.z, __fmaf_rn(x1, E.y, __fmul_rn(x0, E.x)));
            const float d  = __fadd_rn(__fsub_rn(xx, __fadd_rn(xe, xe)), E.w);
            if (d < pbest) { pbest = d; pj = j; }   // strict <: first index wins
        }
        if (pbest < best) { best = pbest; bj = p * 64 + pj; }
    }

    // cross-lane argmin over the 16 c-lanes of this row (butterfly -> all lanes)
    u64 key = ((u64)__float_as_uint(best) << 32) | (unsigned)(bj * 16 + c);
    #pragma unroll
    for (int off = 1; off < 16; off <<= 1) {
        const u64 other = __shfl_xor(key, off, 64);
        if (other < key) key = other;
    }

    float s = 0.0f;
    if (c == 0) {
        const unsigned idx = (unsigned)(key & 0xffffffffULL);
        const float e0 = emb[3 * idx + 0];
        const float e1 = emb[3 * idx + 1];
        const float e2 = emb[3 * idx + 2];
        out_quant[3 * row + 0] = __fadd_rn(x0, __fsub_rn(e0, x0));
        out_quant[3 * row + 1] = __fadd_rn(x1, __fsub_rn(e1, x1));
        out_quant[3 * row + 2] = __fadd_rn(x2, __fsub_rn(e2, x2));
        out_idx[row] = (float)idx;
        const float d0 = e0 - x0, d1 = e1 - x1, d2 = e2 - x2;
        s = d0 * d0 + d1 * d1 + d2 * d2;
    }

    // deterministic block partial: full-wave butterfly (zeros from c!=0 lanes)
    #pragma unroll
    for (int off = 1; off < 64; off <<= 1) s += __shfl_xor(s, off, 64);
    if ((tid & 63) == 0) wsum[tid >> 6] = s;
    __syncthreads();
    if (tid == 0) {
        float t = 0.0f;
        #pragma unroll
        for (int w = 0; w < BLOCK / 64; ++w) t += wsum[w];
        partial[blockIdx.x] = t;
    }
}

// ---------------------------------------------------------------------------
// Reduce GRID block partials -> vq_loss = m + 0.25*m, m = mean(sq)
// ---------------------------------------------------------------------------
__global__ __launch_bounds__(GRID) void vq_loss_kernel(
    const float* __restrict__ partial, float* __restrict__ out_loss)
{
    __shared__ float wsum[GRID / 64];
    float s = partial[threadIdx.x];
    #pragma unroll
    for (int off = 1; off < 64; off <<= 1) s += __shfl_xor(s, off, 64);
    if ((threadIdx.x & 63) == 0) wsum[threadIdx.x >> 6] = s;
    __syncthreads();
    if (threadIdx.x == 0) {
        float t = 0.0f;
        #pragma unroll
        for (int w = 0; w < GRID / 64; ++w) t += wsum[w];
        const float m = t / (float)(N_ROWS * 3);
        out_loss[0] = __fadd_rn(m, __fmul_rn(0.25f, m));
    }
}

extern "C" void kernel_launch(void* const* d_in, const int* in_sizes, int n_in,
                              void* d_out, int out_size, void* d_ws, size_t ws_size,
                              hipStream_t stream)
{
    const float* feats = (const float*)d_in[0];   // [4,4096,3] f32
    const float* emb   = (const float*)d_in[1];   // [8192,3]   f32
    float* out = (float*)d_out;
    float* partial = (float*)d_ws;

    vq_main_kernel<<<GRID, BLOCK, 0, stream>>>(
        feats, emb, out, out + (size_t)N_ROWS * 3, partial);
    vq_loss_kernel<<<1, GRID, 0, stream>>>(partial, out + (size_t)N_ROWS * 4);
}